// Round 1
// baseline (353.452 us; speedup 1.0000x reference)
//
#include <hip/hip_runtime.h>

// FirstBlockTexture: fused facet pipeline + atomic facet->vertex scatter.
//
// Math (per facet f, lane o in [0,64)):
//   B[i*3+c]   = sum_t bary[3f+t][i] * tex[3f+t][c]            (9 uniform vals)
//   Tnet[o]    = relu( (sum_j B[j] W_f2f[j][o]) / num_tex[f] + b_f2f[o] )
//   Gnet[o]    = relu( sum_g geo[f][g] W_mlp[g][o] + b_mlp[o] )
//   net[c]     = c<64 ? Tnet[c] : Gnet[c-64]
//   ct[2c+d]   = (sum_k filt[f][k] W_dw[k][c][d]) * net[c]      (lane o owns c=o, c=o+64)
//   y[o]       = sum_r ct[r] W_pw[r][o]                         (W_pw folded before scatter)
//   out[v][o] += y[o] for each v in face[f]  (atomic; mean+bias+relu in finalize)

#define WPW_FLOATS (256 * 64)

__global__ __launch_bounds__(256, 2) void facet_kernel(
    const float* __restrict__ geo, const float* __restrict__ tex,
    const float* __restrict__ bary, const int* __restrict__ numtex,
    const int* __restrict__ face, const float* __restrict__ filt,
    const float* __restrict__ Wf2f, const float* __restrict__ bf2f,
    const float* __restrict__ Wmlp, const float* __restrict__ bmlp,
    const float* __restrict__ Wdw, const float* __restrict__ Wpw,
    float* __restrict__ out, int NF)
{
    extern __shared__ float smem[];
    float* sWpw   = smem;                 // 16384 floats (64 KB), shared by block
    float* sCtAll = smem + WPW_FLOATS;    // 4 waves * 4 facets * 256 floats (16 KB)

    // Stage W_pw into LDS once per block (amortized over ~100 facets/wave).
    for (int i = threadIdx.x; i < WPW_FLOATS / 4; i += 256)
        ((float4*)sWpw)[i] = ((const float4*)Wpw)[i];
    __syncthreads();

    const int lane = threadIdx.x & 63;
    const int wid  = __builtin_amdgcn_readfirstlane(threadIdx.x >> 6);
    float* sCt = sCtAll + wid * 1024;     // wave-private 4x256 slice

    // Per-lane weight registers (loaded once).
    float wf[9], wm[8];
#pragma unroll
    for (int j = 0; j < 9; ++j) wf[j] = Wf2f[j * 64 + lane];
#pragma unroll
    for (int g = 0; g < 8; ++g) wm[g] = Wmlp[g * 64 + lane];
    float wdw0[27], wdw1[27], wdw2[27], wdw3[27];   // lane's 4 channels of W_dw
#pragma unroll
    for (int k = 0; k < 27; ++k) {
        float2 a = *(const float2*)(Wdw + k * 256 + 2 * lane);
        float2 b = *(const float2*)(Wdw + k * 256 + 128 + 2 * lane);
        wdw0[k] = a.x; wdw1[k] = a.y; wdw2[k] = b.x; wdw3[k] = b.y;
    }
    const float bfv = bf2f[lane];
    const float bmv = bmlp[lane];

    const int nquads = (NF + 3) >> 2;
    const int gw = blockIdx.x * 4 + wid;
    const int nw = gridDim.x * 4;

    for (int q = gw; q < nquads; q += nw) {
        const int f0 = q * 4;

        // ---- per-facet front end: net + mixed depthwise kernel -> ct in LDS ----
#pragma unroll
        for (int fi = 0; fi < 4; ++fi) {
            const int f = f0 + fi;
            const bool valid = (f < NF);
            const int fc_ = valid ? f : (NF - 1);   // clamp to avoid OOB loads

            float Bm[9] = {0, 0, 0, 0, 0, 0, 0, 0, 0};
#pragma unroll
            for (int t = 0; t < 3; ++t) {
                const float* bp = bary + (size_t)(3 * fc_ + t) * 3;
                const float* tp = tex  + (size_t)(3 * fc_ + t) * 3;
                const float b0 = bp[0], b1 = bp[1], b2 = bp[2];
                const float t0 = tp[0], t1 = tp[1], t2 = tp[2];
                Bm[0] = fmaf(b0, t0, Bm[0]); Bm[1] = fmaf(b0, t1, Bm[1]); Bm[2] = fmaf(b0, t2, Bm[2]);
                Bm[3] = fmaf(b1, t0, Bm[3]); Bm[4] = fmaf(b1, t1, Bm[4]); Bm[5] = fmaf(b1, t2, Bm[5]);
                Bm[6] = fmaf(b2, t0, Bm[6]); Bm[7] = fmaf(b2, t1, Bm[7]); Bm[8] = fmaf(b2, t2, Bm[8]);
            }
            float tn = 0.f;
#pragma unroll
            for (int j = 0; j < 9; ++j) tn = fmaf(Bm[j], wf[j], tn);
            tn = fmaxf(tn / (float)numtex[fc_] + bfv, 0.f);

            float gn = 0.f;
#pragma unroll
            for (int g = 0; g < 8; ++g) gn = fmaf(geo[(size_t)fc_ * 8 + g], wm[g], gn);
            gn = fmaxf(gn + bmv, 0.f);

            if (!valid) { tn = 0.f; gn = 0.f; }   // tail facets contribute zeros

            float mk0 = 0.f, mk1 = 0.f, mk2 = 0.f, mk3 = 0.f;
#pragma unroll
            for (int k = 0; k < 27; ++k) {
                const float fcv = filt[(size_t)fc_ * 27 + k];   // wave-uniform -> s_load
                mk0 = fmaf(fcv, wdw0[k], mk0);
                mk1 = fmaf(fcv, wdw1[k], mk1);
                mk2 = fmaf(fcv, wdw2[k], mk2);
                mk3 = fmaf(fcv, wdw3[k], mk3);
            }
            float* ctf = sCt + fi * 256;
            ctf[2 * lane]           = mk0 * tn;
            ctf[2 * lane + 1]       = mk1 * tn;
            ctf[128 + 2 * lane]     = mk2 * gn;
            ctf[128 + 2 * lane + 1] = mk3 * gn;
        }
        // wave-private LDS: same wave wrote & reads; compiler inserts lgkmcnt waits.

        // ---- y = ct @ W_pw for 4 facets, sharing the W_pw LDS reads ----
        float y0 = 0.f, y1 = 0.f, y2 = 0.f, y3 = 0.f;
#pragma unroll 4
        for (int rb = 0; rb < 64; ++rb) {
            const float w0 = sWpw[(4 * rb + 0) * 64 + lane];
            const float w1 = sWpw[(4 * rb + 1) * 64 + lane];
            const float w2 = sWpw[(4 * rb + 2) * 64 + lane];
            const float w3 = sWpw[(4 * rb + 3) * 64 + lane];
            const float4 c0 = ((const float4*)(sCt +   0))[rb];   // broadcast reads
            const float4 c1 = ((const float4*)(sCt + 256))[rb];
            const float4 c2 = ((const float4*)(sCt + 512))[rb];
            const float4 c3 = ((const float4*)(sCt + 768))[rb];
            y0 = fmaf(c0.x, w0, y0); y0 = fmaf(c0.y, w1, y0); y0 = fmaf(c0.z, w2, y0); y0 = fmaf(c0.w, w3, y0);
            y1 = fmaf(c1.x, w0, y1); y1 = fmaf(c1.y, w1, y1); y1 = fmaf(c1.z, w2, y1); y1 = fmaf(c1.w, w3, y1);
            y2 = fmaf(c2.x, w0, y2); y2 = fmaf(c2.y, w1, y2); y2 = fmaf(c2.z, w2, y2); y2 = fmaf(c2.w, w3, y2);
            y3 = fmaf(c3.x, w0, y3); y3 = fmaf(c3.y, w1, y3); y3 = fmaf(c3.z, w2, y3); y3 = fmaf(c3.w, w3, y3);
        }

        // ---- scatter y to the 3 corner vertices (coalesced across lanes) ----
#pragma unroll
        for (int fi = 0; fi < 4; ++fi) {
            const int f = f0 + fi;
            if (f >= NF) break;
            const float yv = (fi == 0) ? y0 : (fi == 1) ? y1 : (fi == 2) ? y2 : y3;
            const int v0 = face[3 * f + 0];
            const int v1 = face[3 * f + 1];
            const int v2 = face[3 * f + 2];
            atomicAdd(out + (size_t)v0 * 64 + lane, yv);
            atomicAdd(out + (size_t)v1 * 64 + lane, yv);
            atomicAdd(out + (size_t)v2 * 64 + lane, yv);
        }
    }
}

__global__ void finalize_kernel(float* __restrict__ out, const int* __restrict__ nfc,
                                const float* __restrict__ bpw, int total)
{
    const int tid = blockIdx.x * blockDim.x + threadIdx.x;
    if (tid >= total) return;
    const int v = tid >> 6;
    const int o = tid & 63;
    const int c = nfc[v];
    const float cnt = (float)(c > 0 ? c : 1);
    out[tid] = fmaxf(out[tid] / cnt + bpw[o], 0.f);
}

extern "C" void kernel_launch(void* const* d_in, const int* in_sizes, int n_in,
                              void* d_out, int out_size, void* d_ws, size_t ws_size,
                              hipStream_t stream)
{
    const float* geo    = (const float*)d_in[0];   // [NF,8]
    const float* tex    = (const float*)d_in[1];   // [T,3]
    const float* bary   = (const float*)d_in[2];   // [T,3]
    const int*   numtex = (const int*)  d_in[3];   // [NF]
    const int*   face   = (const int*)  d_in[4];   // [NF,3]
    const int*   nfc    = (const int*)  d_in[5];   // [NV]
    // d_in[6] full_vt_map unused (scatter by face is the same multiset)
    const float* filt   = (const float*)d_in[7];   // [NF,27]
    const float* Wf2f   = (const float*)d_in[8];   // [9,64]
    const float* bf2f   = (const float*)d_in[9];   // [64]
    const float* Wmlp   = (const float*)d_in[10];  // [8,64]
    const float* bmlp   = (const float*)d_in[11];  // [64]
    const float* Wdw    = (const float*)d_in[12];  // [27,128,2]
    const float* Wpw    = (const float*)d_in[13];  // [256,64]
    const float* bpw    = (const float*)d_in[14];  // [64]
    float* out = (float*)d_out;

    const int NF = in_sizes[0] / 8;
    const int NV = in_sizes[5];

    hipMemsetAsync(d_out, 0, (size_t)out_size * sizeof(float), stream);

    const size_t shmem = (size_t)(WPW_FLOATS + 4 * 4 * 256) * sizeof(float);  // 81920 B
    hipLaunchKernelGGL(facet_kernel, dim3(512), dim3(256), shmem, stream,
                       geo, tex, bary, numtex, face, filt,
                       Wf2f, bf2f, Wmlp, bmlp, Wdw, Wpw, out, NF);

    const int total = NV * 64;
    hipLaunchKernelGGL(finalize_kernel, dim3((total + 255) / 256), dim3(256), 0, stream,
                       out, nfc, bpw, total);
}

// Round 2
// 167.159 us; speedup vs baseline: 2.1145x; 2.1145x over previous
//
#include <hip/hip_runtime.h>

// FirstBlockTexture — full-MFMA facet pipeline.
// Per wave: 16 facets. GEMMs (all mfma_f32_16x16x32_bf16):
//   Tnet16[16,64] = Bm16[16,9→32] @ Wf2f          (then /numtex + b, relu)
//   Gnet16[16,64] = geo16[16,8→32] @ Wmlp         (then + b, relu)
//   mk  [16,256] = filt16[16,27→32] @ Wdw         (D-layout)
//   ct = mk ⊙ net   (net fetched via static __shfl from Tnet/Gnet D-frags)
//   ct → LDS (bf16, XOR-swizzled) → A-frags
//   y   [16,64]  = ct[16,256] @ Wpw               (W_pw folded before scatter)
//   out[v][o] += y  for 3 corners (atomic); mean+bias+relu in finalize.
// All weight B-fragments pre-packed bf16 in ws by prep_kernel (coalesced 16B/lane).

typedef float f32x4 __attribute__((ext_vector_type(4)));
typedef short s16x8 __attribute__((ext_vector_type(8)));
typedef int   i32x4 __attribute__((ext_vector_type(4)));

__device__ __forceinline__ short f2bf(float x) {
    union { float f; unsigned u; } v; v.f = x;
    unsigned r = (v.u + 0x7fffu + ((v.u >> 16) & 1u)) >> 16;   // RNE
    return (short)r;
}

// ws frag table: 56 segments * 64 lanes * 16B = 57344 B
//   seg 0..3  : Wf2f  B-frags (ntile)        K=9  pad32
//   seg 4..7  : Wmlp  B-frags (ntile)        K=8  pad32
//   seg 8..23 : Wdw   B-frags (ntile2)       K=27 pad32
//   seg 24..55: Wpw   B-frags (nt*8+kc)      K=256
__global__ void prep_kernel(const float* __restrict__ Wf2f, const float* __restrict__ Wmlp,
                            const float* __restrict__ Wdw,  const float* __restrict__ Wpw,
                            s16x8* __restrict__ wsAll)
{
    int gid = blockIdx.x * 256 + threadIdx.x;
    if (gid >= 56 * 64) return;
    int l = gid & 63, seg = gid >> 6;
    int k4 = l >> 4, o = l & 15;
    s16x8 v;
    if (seg < 4) {
#pragma unroll
        for (int j = 0; j < 8; ++j) { int k = k4 * 8 + j; v[j] = (k < 9) ? f2bf(Wf2f[k * 64 + seg * 16 + o]) : (short)0; }
    } else if (seg < 8) {
        int nt = seg - 4;
#pragma unroll
        for (int j = 0; j < 8; ++j) { int k = k4 * 8 + j; v[j] = (k < 8) ? f2bf(Wmlp[k * 64 + nt * 16 + o]) : (short)0; }
    } else if (seg < 24) {
        int nt2 = seg - 8;
#pragma unroll
        for (int j = 0; j < 8; ++j) { int k = k4 * 8 + j; v[j] = (k < 27) ? f2bf(Wdw[k * 256 + nt2 * 16 + o]) : (short)0; }
    } else {
        int s = seg - 24, nt = s >> 3, kc = s & 7;
#pragma unroll
        for (int j = 0; j < 8; ++j) { int k = kc * 32 + k4 * 8 + j; v[j] = f2bf(Wpw[k * 64 + nt * 16 + o]); }
    }
    wsAll[gid] = v;
}

__global__ __launch_bounds__(256, 4) void facet_kernel(
    const float* __restrict__ geo, const float* __restrict__ tex,
    const float* __restrict__ bary, const int* __restrict__ numtex,
    const int* __restrict__ face, const float* __restrict__ filt,
    const float* __restrict__ bf2f, const float* __restrict__ bmlp,
    const s16x8* __restrict__ wsAll, float* __restrict__ out,
    int NF, int ntiles)
{
    __shared__ char sCtAll[4][8192];          // per-wave [16][256] bf16, XOR-swizzled
    const int l   = threadIdx.x & 63;
    const int wid = threadIdx.x >> 6;
    const int tile = blockIdx.x * 4 + wid;
    if (tile >= ntiles) return;               // no barriers in this kernel -> safe
    const int f0 = tile * 16;
    const int o16 = l & 15, k4 = l >> 4;
    char* sCt = sCtAll[wid];

    const s16x8* wsF2f = wsAll;
    const s16x8* wsMlp = wsAll + 4 * 64;
    const s16x8* wsWdw = wsAll + 8 * 64;
    const s16x8* wsWpw = wsAll + 24 * 64;
    const f32x4 z4 = {0.f, 0.f, 0.f, 0.f};

    // ---- per-lane facet inputs (lane's A-row facet: fl = f0 + o16) ----
    int flr = f0 + o16;
    int fl = (flr < NF) ? flr : (NF - 1);

    // Bm[9] = sum_t outer(bary_t, tex_t)
    const float* bp = bary + 9 * (size_t)fl;
    const float* tp = tex  + 9 * (size_t)fl;
    float Bm[9] = {0.f,0.f,0.f,0.f,0.f,0.f,0.f,0.f,0.f};
#pragma unroll
    for (int t = 0; t < 3; ++t) {
        float b0 = bp[3*t], b1 = bp[3*t+1], b2 = bp[3*t+2];
        float x0 = tp[3*t], x1 = tp[3*t+1], x2 = tp[3*t+2];
        Bm[0] = fmaf(b0, x0, Bm[0]); Bm[1] = fmaf(b0, x1, Bm[1]); Bm[2] = fmaf(b0, x2, Bm[2]);
        Bm[3] = fmaf(b1, x0, Bm[3]); Bm[4] = fmaf(b1, x1, Bm[4]); Bm[5] = fmaf(b1, x2, Bm[5]);
        Bm[6] = fmaf(b2, x0, Bm[6]); Bm[7] = fmaf(b2, x1, Bm[7]); Bm[8] = fmaf(b2, x2, Bm[8]);
    }
    s16x8 aF2f;
    aF2f[0] = f2bf((k4 == 1) ? Bm[8] : Bm[0]);   // k4==1 lane supplies A[k=8]; k>=9 hits zeroed B rows
#pragma unroll
    for (int j = 1; j < 8; ++j) aF2f[j] = f2bf(Bm[j]);

    const float* gp = geo + 8 * (size_t)fl;
    s16x8 aMlp;
#pragma unroll
    for (int j = 0; j < 8; ++j) aMlp[j] = f2bf(gp[j]);   // k4>0 rows hit zeroed B

    const float* fp = filt + 27 * (size_t)fl + k4 * 8;
    s16x8 aFlt;
#pragma unroll
    for (int j = 0; j < 8; ++j) {
        int k = k4 * 8 + j;
        aFlt[j] = (k < 27) ? f2bf(fp[j]) : (short)0;
    }

    // numtex (per D-row facet m = 4*k4 + t) and biases
    i32x4 nm4;
    if (f0 + 16 <= NF) {
        nm4 = *(const i32x4*)(numtex + f0 + 4 * k4);
    } else {
#pragma unroll
        for (int t = 0; t < 4; ++t) { int idx = f0 + 4 * k4 + t; nm4[t] = numtex[idx < NF ? idx : NF - 1]; }
    }
    float invn[4];
#pragma unroll
    for (int t = 0; t < 4; ++t) invn[t] = 1.0f / (float)nm4[t];
    float bfo[4], bmo[4];
#pragma unroll
    for (int nt = 0; nt < 4; ++nt) { bfo[nt] = bf2f[nt * 16 + o16]; bmo[nt] = bmlp[nt * 16 + o16]; }

    // ---- Tnet / Gnet ----
    float tn[4][4], gn[4][4];                // [nt][t], D-layout: row m=4*k4+t, col nt*16+o16
#pragma unroll
    for (int nt = 0; nt < 4; ++nt) {
        f32x4 aT = __builtin_amdgcn_mfma_f32_16x16x32_bf16(aF2f, wsF2f[nt * 64 + l], z4, 0, 0, 0);
        f32x4 aG = __builtin_amdgcn_mfma_f32_16x16x32_bf16(aMlp, wsMlp[nt * 64 + l], z4, 0, 0, 0);
#pragma unroll
        for (int t = 0; t < 4; ++t) {
            bool mv = (f0 + 4 * k4 + t) < NF;
            float tv = fmaxf(fmaf(aT[t], invn[t], bfo[nt]), 0.f);
            float gv = fmaxf(aG[t] + bmo[nt], 0.f);
            tn[nt][t] = mv ? tv : 0.f;
            gn[nt][t] = mv ? gv : 0.f;
        }
    }

    // ---- GEMM1: mk = filt16 @ Wdw ; ct = mk * net -> sCt (bf16, swizzled) ----
#pragma unroll
    for (int nt2 = 0; nt2 < 16; ++nt2) {
        f32x4 acc = __builtin_amdgcn_mfma_f32_16x16x32_bf16(aFlt, wsWdw[nt2 * 64 + l], z4, 0, 0, 0);
        const int srcl = k4 * 16 + (nt2 & 1) * 8 + (o16 >> 1);   // lane holding net[m][c]
        const int r = nt2 * 16 + o16;
#pragma unroll
        for (int t = 0; t < 4; ++t) {
            float netv = (nt2 < 8) ? __shfl(tn[nt2 >> 1][t], srcl, 64)
                                   : __shfl(gn[(nt2 - 8) >> 1][t], srcl, 64);
            float cv = acc[t] * netv;
            const int m = 4 * k4 + t;
            *(short*)(sCt + m * 512 + ((r * 2) ^ ((m & 7) << 4))) = f2bf(cv);
        }
    }

    // ---- GEMM2: y = ct @ Wpw ----  (same-wave LDS write->read; compiler waits lgkmcnt)
    f32x4 acc2[4] = {z4, z4, z4, z4};
#pragma unroll
    for (int kc = 0; kc < 8; ++kc) {
        s16x8 a2 = *(const s16x8*)(sCt + o16 * 512 + ((kc * 64 + k4 * 16) ^ ((o16 & 7) << 4)));
#pragma unroll
        for (int nt = 0; nt < 4; ++nt)
            acc2[nt] = __builtin_amdgcn_mfma_f32_16x16x32_bf16(a2, wsWpw[(nt * 8 + kc) * 64 + l], acc2[nt], 0, 0, 0);
    }

    // ---- scatter to 3 corner vertices ----
    int fidx = 3 * f0 + l;
    int fmax = 3 * NF - 1;
    int fvi = (l < 48) ? face[fidx < fmax ? fidx : fmax] : 0;
#pragma unroll
    for (int t = 0; t < 4; ++t) {
        const int m = 4 * k4 + t;
        const bool mv = (f0 + m) < NF;
#pragma unroll
        for (int j = 0; j < 3; ++j) {
            int v = __shfl(fvi, 3 * m + j, 64);
            if (mv) {
#pragma unroll
                for (int nt = 0; nt < 4; ++nt)
                    atomicAdd(out + (size_t)v * 64 + nt * 16 + o16, acc2[nt][t]);
            }
        }
    }
}

__global__ void finalize_kernel(float* __restrict__ out, const int* __restrict__ nfc,
                                const float* __restrict__ bpw, int total)
{
    const int tid = blockIdx.x * blockDim.x + threadIdx.x;
    if (tid >= total) return;
    const int v = tid >> 6;
    const int o = tid & 63;
    const int c = nfc[v];
    const float cnt = (float)(c > 0 ? c : 1);
    out[tid] = fmaxf(out[tid] / cnt + bpw[o], 0.f);
}

extern "C" void kernel_launch(void* const* d_in, const int* in_sizes, int n_in,
                              void* d_out, int out_size, void* d_ws, size_t ws_size,
                              hipStream_t stream)
{
    const float* geo    = (const float*)d_in[0];   // [NF,8]
    const float* tex    = (const float*)d_in[1];   // [T,3]
    const float* bary   = (const float*)d_in[2];   // [T,3]
    const int*   numtex = (const int*)  d_in[3];   // [NF]
    const int*   face   = (const int*)  d_in[4];   // [NF,3]
    const int*   nfc    = (const int*)  d_in[5];   // [NV]
    // d_in[6] full_vt_map unused (atomic scatter over face is the same multiset)
    const float* filt   = (const float*)d_in[7];   // [NF,27]
    const float* Wf2f   = (const float*)d_in[8];   // [9,64]
    const float* bf2f   = (const float*)d_in[9];   // [64]
    const float* Wmlp   = (const float*)d_in[10];  // [8,64]
    const float* bmlp   = (const float*)d_in[11];  // [64]
    const float* Wdw    = (const float*)d_in[12];  // [27,128,2]
    const float* Wpw    = (const float*)d_in[13];  // [256,64]
    const float* bpw    = (const float*)d_in[14];  // [64]
    float* out = (float*)d_out;

    const int NF = in_sizes[0] / 8;
    const int NV = in_sizes[5];
    const int ntiles = (NF + 15) / 16;

    s16x8* wsAll = (s16x8*)d_ws;                   // 57344 B of frag tables

    hipMemsetAsync(d_out, 0, (size_t)out_size * sizeof(float), stream);

    hipLaunchKernelGGL(prep_kernel, dim3(14), dim3(256), 0, stream,
                       Wf2f, Wmlp, Wdw, Wpw, wsAll);

    hipLaunchKernelGGL(facet_kernel, dim3((ntiles + 3) / 4), dim3(256), 0, stream,
                       geo, tex, bary, numtex, face, filt, bf2f, bmlp, wsAll, out, NF, ntiles);

    const int total = NV * 64;
    hipLaunchKernelGGL(finalize_kernel, dim3((total + 255) / 256), dim3(256), 0, stream,
                       out, nfc, bpw, total);
}

// Round 3
// 91.507 us; speedup vs baseline: 3.8626x; 1.8267x over previous
//
#include <hip/hip_runtime.h>

// FirstBlockTexture — full-MFMA facet pipeline + CSR gather (no atomics).
// facet_kernel: per wave 16 facets, all GEMMs on mfma_f32_16x16x32_bf16,
//   writes y[NF,64] fp32 to ws (W_pw folded in before the vertex reduce).
// scanA/B/C: exclusive prefix-scan of full_nf_count -> CSR row starts.
// vertex_kernel: wave per vertex, lane=channel; gathers y rows via vt_map,
//   mean + b_pw + relu fused. Fallback to atomic scatter if ws too small.

typedef float f32x4 __attribute__((ext_vector_type(4)));
typedef short s16x8 __attribute__((ext_vector_type(8)));
typedef int   i32x4 __attribute__((ext_vector_type(4)));

__device__ __forceinline__ short f2bf(float x) {
    union { float f; unsigned u; } v; v.f = x;
    unsigned r = (v.u + 0x7fffu + ((v.u >> 16) & 1u)) >> 16;   // RNE
    return (short)r;
}

// ws frag table: 56 segments * 64 lanes * 16B = 57344 B
__global__ void prep_kernel(const float* __restrict__ Wf2f, const float* __restrict__ Wmlp,
                            const float* __restrict__ Wdw,  const float* __restrict__ Wpw,
                            s16x8* __restrict__ wsAll)
{
    int gid = blockIdx.x * 256 + threadIdx.x;
    if (gid >= 56 * 64) return;
    int l = gid & 63, seg = gid >> 6;
    int k4 = l >> 4, o = l & 15;
    s16x8 v;
    if (seg < 4) {
#pragma unroll
        for (int j = 0; j < 8; ++j) { int k = k4 * 8 + j; v[j] = (k < 9) ? f2bf(Wf2f[k * 64 + seg * 16 + o]) : (short)0; }
    } else if (seg < 8) {
        int nt = seg - 4;
#pragma unroll
        for (int j = 0; j < 8; ++j) { int k = k4 * 8 + j; v[j] = (k < 8) ? f2bf(Wmlp[k * 64 + nt * 16 + o]) : (short)0; }
    } else if (seg < 24) {
        int nt2 = seg - 8;
#pragma unroll
        for (int j = 0; j < 8; ++j) { int k = k4 * 8 + j; v[j] = (k < 27) ? f2bf(Wdw[k * 256 + nt2 * 16 + o]) : (short)0; }
    } else {
        int s = seg - 24, nt = s >> 3, kc = s & 7;
#pragma unroll
        for (int j = 0; j < 8; ++j) { int k = kc * 32 + k4 * 8 + j; v[j] = f2bf(Wpw[k * 64 + nt * 16 + o]); }
    }
    wsAll[gid] = v;
}

// ---------------- prefix scan of nf_count (3 tiny kernels) ----------------
__global__ void scanA(const int* __restrict__ nfc, int* __restrict__ bsum, int NV)
{
    __shared__ int sd[256];
    int b = blockIdx.x, t = threadIdx.x;
    int v0 = b * 512 + 2 * t;
    int e0 = (v0 < NV) ? nfc[v0] : 0;
    int e1 = (v0 + 1 < NV) ? nfc[v0 + 1] : 0;
    sd[t] = e0 + e1;
    __syncthreads();
    for (int off = 128; off > 0; off >>= 1) {
        if (t < off) sd[t] += sd[t + off];
        __syncthreads();
    }
    if (t == 0) bsum[b] = sd[0];
}

__global__ void scanB(const int* __restrict__ bsum, int* __restrict__ boff, int NB)
{
    __shared__ int sd[256];
    int t = threadIdx.x;
    int s = (t < NB) ? bsum[t] : 0;
    sd[t] = s;
    __syncthreads();
    for (int off = 1; off < 256; off <<= 1) {
        int v = (t >= off) ? sd[t - off] : 0;
        __syncthreads();
        sd[t] += v;
        __syncthreads();
    }
    if (t < NB) boff[t] = sd[t] - s;   // exclusive
}

__global__ void scanC(const int* __restrict__ nfc, const int* __restrict__ boff,
                      int* __restrict__ startArr, int NV)
{
    __shared__ int sd[256];
    int b = blockIdx.x, t = threadIdx.x;
    int v0 = b * 512 + 2 * t;
    int e0 = (v0 < NV) ? nfc[v0] : 0;
    int e1 = (v0 + 1 < NV) ? nfc[v0 + 1] : 0;
    int s = e0 + e1;
    sd[t] = s;
    __syncthreads();
    for (int off = 1; off < 256; off <<= 1) {
        int v = (t >= off) ? sd[t - off] : 0;
        __syncthreads();
        sd[t] += v;
        __syncthreads();
    }
    int off0 = boff[b] + sd[t] - s;    // exclusive within-grid offset
    if (v0 < NV) startArr[v0] = off0;
    if (v0 + 1 < NV) startArr[v0 + 1] = off0 + e0;
}

// ---------------- facet pipeline ----------------
__global__ __launch_bounds__(256, 4) void facet_kernel(
    const float* __restrict__ geo, const float* __restrict__ tex,
    const float* __restrict__ bary, const int* __restrict__ numtex,
    const int* __restrict__ face, const float* __restrict__ filt,
    const float* __restrict__ bf2f, const float* __restrict__ bmlp,
    const s16x8* __restrict__ wsAll, float* __restrict__ yws,
    float* __restrict__ out, int NF, int ntiles, int mode)
{
    __shared__ char sCtAll[4][8192];          // per-wave [16][256] bf16, XOR-swizzled
    const int l   = threadIdx.x & 63;
    const int wid = threadIdx.x >> 6;
    const int tile = blockIdx.x * 4 + wid;
    if (tile >= ntiles) return;               // no barriers in this kernel -> safe
    const int f0 = tile * 16;
    const int o16 = l & 15, k4 = l >> 4;
    char* sCt = sCtAll[wid];

    const s16x8* wsF2f = wsAll;
    const s16x8* wsMlp = wsAll + 4 * 64;
    const s16x8* wsWdw = wsAll + 8 * 64;
    const s16x8* wsWpw = wsAll + 24 * 64;
    const f32x4 z4 = {0.f, 0.f, 0.f, 0.f};

    int flr = f0 + o16;
    int fl = (flr < NF) ? flr : (NF - 1);

    // Bm[9] = sum_t outer(bary_t, tex_t)
    const float* bp = bary + 9 * (size_t)fl;
    const float* tp = tex  + 9 * (size_t)fl;
    float Bm[9] = {0.f,0.f,0.f,0.f,0.f,0.f,0.f,0.f,0.f};
#pragma unroll
    for (int t = 0; t < 3; ++t) {
        float b0 = bp[3*t], b1 = bp[3*t+1], b2 = bp[3*t+2];
        float x0 = tp[3*t], x1 = tp[3*t+1], x2 = tp[3*t+2];
        Bm[0] = fmaf(b0, x0, Bm[0]); Bm[1] = fmaf(b0, x1, Bm[1]); Bm[2] = fmaf(b0, x2, Bm[2]);
        Bm[3] = fmaf(b1, x0, Bm[3]); Bm[4] = fmaf(b1, x1, Bm[4]); Bm[5] = fmaf(b1, x2, Bm[5]);
        Bm[6] = fmaf(b2, x0, Bm[6]); Bm[7] = fmaf(b2, x1, Bm[7]); Bm[8] = fmaf(b2, x2, Bm[8]);
    }
    s16x8 aF2f;
    aF2f[0] = f2bf((k4 == 1) ? Bm[8] : Bm[0]);   // k4==1 lane supplies A[k=8]
#pragma unroll
    for (int j = 1; j < 8; ++j) aF2f[j] = f2bf(Bm[j]);

    const float* gp = geo + 8 * (size_t)fl;
    s16x8 aMlp;
#pragma unroll
    for (int j = 0; j < 8; ++j) aMlp[j] = f2bf(gp[j]);

    const float* fp = filt + 27 * (size_t)fl + k4 * 8;
    s16x8 aFlt;
#pragma unroll
    for (int j = 0; j < 8; ++j) {
        int k = k4 * 8 + j;
        aFlt[j] = (k < 27) ? f2bf(fp[j]) : (short)0;
    }

    i32x4 nm4;
    if (f0 + 16 <= NF) {
        nm4 = *(const i32x4*)(numtex + f0 + 4 * k4);
    } else {
#pragma unroll
        for (int t = 0; t < 4; ++t) { int idx = f0 + 4 * k4 + t; nm4[t] = numtex[idx < NF ? idx : NF - 1]; }
    }
    float invn[4];
#pragma unroll
    for (int t = 0; t < 4; ++t) invn[t] = 1.0f / (float)nm4[t];
    float bfo[4], bmo[4];
#pragma unroll
    for (int nt = 0; nt < 4; ++nt) { bfo[nt] = bf2f[nt * 16 + o16]; bmo[nt] = bmlp[nt * 16 + o16]; }

    // ---- Tnet / Gnet ----
    float tn[4][4], gn[4][4];                // [nt][t], D-layout row m=4*k4+t, col nt*16+o16
#pragma unroll
    for (int nt = 0; nt < 4; ++nt) {
        f32x4 aT = __builtin_amdgcn_mfma_f32_16x16x32_bf16(aF2f, wsF2f[nt * 64 + l], z4, 0, 0, 0);
        f32x4 aG = __builtin_amdgcn_mfma_f32_16x16x32_bf16(aMlp, wsMlp[nt * 64 + l], z4, 0, 0, 0);
#pragma unroll
        for (int t = 0; t < 4; ++t) {
            bool mv = (f0 + 4 * k4 + t) < NF;
            float tv = fmaxf(fmaf(aT[t], invn[t], bfo[nt]), 0.f);
            float gv = fmaxf(aG[t] + bmo[nt], 0.f);
            tn[nt][t] = mv ? tv : 0.f;
            gn[nt][t] = mv ? gv : 0.f;
        }
    }

    // ---- GEMM1: mk = filt16 @ Wdw ; ct = mk * net -> sCt (bf16, swizzled) ----
#pragma unroll
    for (int nt2 = 0; nt2 < 16; ++nt2) {
        f32x4 acc = __builtin_amdgcn_mfma_f32_16x16x32_bf16(aFlt, wsWdw[nt2 * 64 + l], z4, 0, 0, 0);
        const int srcl = k4 * 16 + (nt2 & 1) * 8 + (o16 >> 1);
        const int r = nt2 * 16 + o16;
#pragma unroll
        for (int t = 0; t < 4; ++t) {
            float netv = (nt2 < 8) ? __shfl(tn[nt2 >> 1][t], srcl, 64)
                                   : __shfl(gn[(nt2 - 8) >> 1][t], srcl, 64);
            float cv = acc[t] * netv;
            const int m = 4 * k4 + t;
            *(short*)(sCt + m * 512 + ((r * 2) ^ ((m & 7) << 4))) = f2bf(cv);
        }
    }

    // ---- GEMM2: y = ct @ Wpw ----
    f32x4 acc2[4] = {z4, z4, z4, z4};
#pragma unroll
    for (int kc = 0; kc < 8; ++kc) {
        s16x8 a2 = *(const s16x8*)(sCt + o16 * 512 + ((kc * 64 + k4 * 16) ^ ((o16 & 7) << 4)));
#pragma unroll
        for (int nt = 0; nt < 4; ++nt)
            acc2[nt] = __builtin_amdgcn_mfma_f32_16x16x32_bf16(a2, wsWpw[(nt * 8 + kc) * 64 + l], acc2[nt], 0, 0, 0);
    }

    if (mode == 0) {
        // ---- store y rows (coalesced; consumed by vertex_kernel) ----
#pragma unroll
        for (int nt = 0; nt < 4; ++nt)
#pragma unroll
            for (int t = 0; t < 4; ++t) {
                const int m = 4 * k4 + t, f = f0 + m;
                if (f < NF) yws[(size_t)f * 64 + nt * 16 + o16] = acc2[nt][t];
            }
    } else {
        // ---- fallback: atomic scatter ----
        int fidx = 3 * f0 + l;
        int fmax = 3 * NF - 1;
        int fvi = (l < 48) ? face[fidx < fmax ? fidx : fmax] : 0;
#pragma unroll
        for (int t = 0; t < 4; ++t) {
            const int m = 4 * k4 + t;
            const bool mv = (f0 + m) < NF;
#pragma unroll
            for (int j = 0; j < 3; ++j) {
                int v = __shfl(fvi, 3 * m + j, 64);
                if (mv) {
#pragma unroll
                    for (int nt = 0; nt < 4; ++nt)
                        atomicAdd(out + (size_t)v * 64 + nt * 16 + o16, acc2[nt][t]);
                }
            }
        }
    }
}

// ---------------- CSR gather: vsum/mean + bias + relu ----------------
__global__ __launch_bounds__(256) void vertex_kernel(
    const float* __restrict__ yws, const int* __restrict__ vt_map,
    const int* __restrict__ startArr, const int* __restrict__ nfc,
    const float* __restrict__ bpw, float* __restrict__ out, int NV)
{
    const int wid  = __builtin_amdgcn_readfirstlane(threadIdx.x >> 6);
    const int lane = threadIdx.x & 63;
    const int v = blockIdx.x * 4 + wid;
    if (v >= NV) return;
    const int start = startArr[v];     // wave-uniform -> scalar loads
    const int cnt   = nfc[v];
    float acc = 0.f;
    int i = 0;
    for (; i + 2 <= cnt; i += 2) {     // two independent gathers in flight
        const int fa = vt_map[start + i];
        const int fb = vt_map[start + i + 1];
        const float ya = yws[(size_t)fa * 64 + lane];
        const float yb = yws[(size_t)fb * 64 + lane];
        acc += ya + yb;
    }
    if (i < cnt) acc += yws[(size_t)vt_map[start + i] * 64 + lane];
    const float inv = 1.0f / (float)(cnt > 0 ? cnt : 1);
    out[(size_t)v * 64 + lane] = fmaxf(fmaf(acc, inv, bpw[lane]), 0.f);
}

__global__ void finalize_kernel(float* __restrict__ out, const int* __restrict__ nfc,
                                const float* __restrict__ bpw, int total)
{
    const int tid = blockIdx.x * blockDim.x + threadIdx.x;
    if (tid >= total) return;
    const int v = tid >> 6;
    const int o = tid & 63;
    const int c = nfc[v];
    const float cnt = (float)(c > 0 ? c : 1);
    out[tid] = fmaxf(out[tid] / cnt + bpw[o], 0.f);
}

extern "C" void kernel_launch(void* const* d_in, const int* in_sizes, int n_in,
                              void* d_out, int out_size, void* d_ws, size_t ws_size,
                              hipStream_t stream)
{
    const float* geo    = (const float*)d_in[0];   // [NF,8]
    const float* tex    = (const float*)d_in[1];   // [T,3]
    const float* bary   = (const float*)d_in[2];   // [T,3]
    const int*   numtex = (const int*)  d_in[3];   // [NF]
    const int*   face   = (const int*)  d_in[4];   // [NF,3]
    const int*   nfc    = (const int*)  d_in[5];   // [NV]
    const int*   vtmap  = (const int*)  d_in[6];   // [3*NF]
    const float* filt   = (const float*)d_in[7];   // [NF,27]
    const float* Wf2f   = (const float*)d_in[8];   // [9,64]
    const float* bf2f   = (const float*)d_in[9];   // [64]
    const float* Wmlp   = (const float*)d_in[10];  // [8,64]
    const float* bmlp   = (const float*)d_in[11];  // [64]
    const float* Wdw    = (const float*)d_in[12];  // [27,128,2]
    const float* Wpw    = (const float*)d_in[13];  // [256,64]
    const float* bpw    = (const float*)d_in[14];  // [64]
    float* out = (float*)d_out;

    const int NF = in_sizes[0] / 8;
    const int NV = in_sizes[5];
    const int ntiles = (NF + 15) / 16;
    const int NB = (NV + 511) / 512;               // scan blocks (<=256 for NV<=131072)

    // ws layout (256B-aligned segments)
    const size_t offFrag  = 0;
    const size_t offY     = 57344;
    const size_t offStart = offY + (size_t)NF * 64 * sizeof(float);
    const size_t offBsum  = offStart + (((size_t)NV * 4 + 255) & ~(size_t)255);
    const size_t offBoff  = offBsum + 1024;
    const size_t needed   = offBoff + 1024;

    s16x8* wsAll    = (s16x8*)((char*)d_ws + offFrag);
    float* yws      = (float*)((char*)d_ws + offY);
    int*   startArr = (int*)  ((char*)d_ws + offStart);
    int*   bsum     = (int*)  ((char*)d_ws + offBsum);
    int*   boff     = (int*)  ((char*)d_ws + offBoff);

    const bool csr = (ws_size >= needed) && (NB <= 256);
    const int mode = csr ? 0 : 1;

    hipLaunchKernelGGL(prep_kernel, dim3(14), dim3(256), 0, stream,
                       Wf2f, Wmlp, Wdw, Wpw, wsAll);

    if (csr) {
        hipLaunchKernelGGL(scanA, dim3(NB), dim3(256), 0, stream, nfc, bsum, NV);
        hipLaunchKernelGGL(scanB, dim3(1),  dim3(256), 0, stream, bsum, boff, NB);
        hipLaunchKernelGGL(scanC, dim3(NB), dim3(256), 0, stream, nfc, boff, startArr, NV);
    } else {
        hipMemsetAsync(d_out, 0, (size_t)out_size * sizeof(float), stream);
    }

    hipLaunchKernelGGL(facet_kernel, dim3((ntiles + 3) / 4), dim3(256), 0, stream,
                       geo, tex, bary, numtex, face, filt, bf2f, bmlp, wsAll,
                       yws, out, NF, ntiles, mode);

    if (csr) {
        hipLaunchKernelGGL(vertex_kernel, dim3((NV + 3) / 4), dim3(256), 0, stream,
                           yws, vtmap, startArr, nfc, bpw, out, NV);
    } else {
        const int total = NV * 64;
        hipLaunchKernelGGL(finalize_kernel, dim3((total + 255) / 256), dim3(256), 0, stream,
                           out, nfc, bpw, total);
    }
}